// Round 6
// baseline (132.354 us; speedup 1.0000x reference)
//
#include <hip/hip_runtime.h>
#include <hip/hip_bf16.h>

// ScaledDotProdAttn (no softmax): attn = (q@k^T)/8 ; out = attn@v
// B=32, SQ=SK=2048, D=64, fp32 in/out. d_out = [out] ++ [attn]
// R6 = R5 + deferred attn stores (write-late by one tile): S is read back to
// registers at end of tile kt, NT-stored at the top of tile kt+1, so the
// barrier's vmcnt(0) drain finds them already retired. Everything else R5.

typedef __attribute__((ext_vector_type(4))) float        f32x4;
typedef __attribute__((ext_vector_type(8))) short        s16x8;
typedef __attribute__((ext_vector_type(2))) unsigned int u32x2;
typedef __attribute__((ext_vector_type(4))) unsigned int u32x4;

#define NB    32
#define SQL   2048
#define SKL   2048
#define DD    64
#define QBLK  128
#define KBLK  64
#define NTILES (SKL / KBLK)

// LDS (48 KB -> 2 blocks/CU with 512-thread blocks = 16 waves/CU):
//   [0    ,16384) K dbuf : 2 x (64 keys x 64 bf16), row stride 128 B
//   [16384,32768) V^T dbuf: 2 x (64 d x 64 keys bf16 packed), stride 128 B
//   [32768,49152) S priv : 8 waves x (16 q x 64 k bf16), stride 128 B
#define KOFF 0
#define VOFF 16384
#define SOFF 32768

__device__ __forceinline__ unsigned short f2bf(float f) {
    union { float f; unsigned u; } x; x.f = f;
    unsigned r = x.u + 0x7FFFu + ((x.u >> 16) & 1u);   // RNE
    return (unsigned short)(r >> 16);
}
// swizzles: XOR into byte-addr bits 4..6 (row stride 128 B everywhere)
__device__ __forceinline__ unsigned swzK(unsigned k) { return (k & 7u) << 4; }
__device__ __forceinline__ unsigned swzV(unsigned d) { return (d & 7u) << 4; }
__device__ __forceinline__ unsigned swzS(unsigned q) { return ((q + (q >> 3)) & 7u) << 4; }

__global__ __launch_bounds__(512, 4)
void sdpa_fused(const float* __restrict__ qg, const float* __restrict__ kg,
                const float* __restrict__ vg, float* __restrict__ og,
                float* __restrict__ ag) {
    __shared__ __align__(16) char smem[49152];

    const unsigned tid  = threadIdx.x;
    const unsigned wid  = tid >> 6;          // 0..7
    const unsigned lane = tid & 63u;
    const unsigned l15  = lane & 15u;
    const unsigned l4   = lane >> 4;         // 0..3

    // XCD-aware mapping (R4 win: FETCH 417->43 MB)
    const unsigned xcd = blockIdx.x & 7u;
    const unsigned loc = blockIdx.x >> 3;        // 0..63
    const unsigned b   = xcd * 4u + (loc >> 4);  // batch
    const unsigned qt  = loc & 15u;              // q-tile in batch
    const unsigned qbase = qt * QBLK;

    // staging maps (512 threads)
    const unsigned kr = tid >> 3, kc = tid & 7u;   // K: row 0..63, 32B chunk
    const unsigned vt = tid >> 4, vc = tid & 15u;  // V: key-pair 0..31, d-chunk

    // ---- Q -> A-fragments directly from global (scale folded in) ----
    s16x8 aq[2];
    {
        const float* qrow = qg + ((size_t)b * SQL + qbase + wid * 16 + l15) * DD;
        #pragma unroll
        for (int ks = 0; ks < 2; ++ks) {
            f32x4 f0 = *(const f32x4*)(qrow + ks * 32 + l4 * 8);
            f32x4 f1 = *(const f32x4*)(qrow + ks * 32 + l4 * 8 + 4);
            #pragma unroll
            for (int j = 0; j < 4; ++j) {
                aq[ks][j]     = (short)f2bf(f0[j] * 0.125f);
                aq[ks][j + 4] = (short)f2bf(f1[j] * 0.125f);
            }
        }
    }

    f32x4 acc_o[4];
    #pragma unroll
    for (int n = 0; n < 4; ++n) acc_o[n] = (f32x4){0.f, 0.f, 0.f, 0.f};

    const float* kbat = kg + (size_t)b * SKL * DD;
    const float* vbat = vg + (size_t)b * SKL * DD;

    auto stage = [&](int kt, int sel) {
        const float* ksrc = kbat + (size_t)kt * KBLK * DD;
        const float* vsrc = vbat + (size_t)kt * KBLK * DD;
        f32x4 k0 = *(const f32x4*)(ksrc + kr * DD + kc * 8);
        f32x4 k1 = *(const f32x4*)(ksrc + kr * DD + kc * 8 + 4);
        s16x8 h;
        #pragma unroll
        for (int j = 0; j < 4; ++j) {
            h[j]     = (short)f2bf(k0[j]);
            h[j + 4] = (short)f2bf(k1[j]);
        }
        *(s16x8*)(smem + KOFF + sel * 8192 + kr * 128 + ((kc * 16) ^ swzK(kr))) = h;
        f32x4 v0 = *(const f32x4*)(vsrc + (2 * vt) * DD + vc * 4);
        f32x4 v1 = *(const f32x4*)(vsrc + (2 * vt + 1) * DD + vc * 4);
        #pragma unroll
        for (int j = 0; j < 4; ++j) {
            unsigned d = vc * 4 + (unsigned)j;
            unsigned pack = (unsigned)f2bf(v0[j]) | ((unsigned)f2bf(v1[j]) << 16);
            *(unsigned*)(smem + VOFF + sel * 8192 + d * 128 + ((vt * 4) ^ swzV(d))) = pack;
        }
    };

    stage(0, 0);
    __syncthreads();

    char* sbase = smem + SOFF + wid * 2048;   // wave-private S: 16 x 128 B
    const unsigned rr = lane >> 3, cc = lane & 7u;  // attn readback map
    float* const awave = ag + ((size_t)b * SQL + qbase + wid * 16) * SKL;

    u32x2 pbuf[4];   // deferred attn values (bf16-packed), stored next tile

    auto dostores = [&](int t) {
        float* abase = awave + (size_t)t * KBLK;
        #pragma unroll
        for (int h = 0; h < 4; ++h) {
            unsigned q  = (h & 1) * 8 + rr;
            unsigned k4 = (h >> 1) * 32 + cc * 4;
            u32x2 p = pbuf[h];
            u32x4 w;
            w[0] = p[0] << 16; w[1] = p[0] & 0xFFFF0000u;
            w[2] = p[1] << 16; w[3] = p[1] & 0xFFFF0000u;
            __builtin_nontemporal_store(w, (u32x4*)(abase + (size_t)q * SKL + k4));
        }
    };

    for (int kt = 0; kt < NTILES; ++kt) {
        const int cur = kt & 1;

        // deferred attn stores for tile kt-1: a full tile of work before the
        // next barrier's vmcnt(0) drain
        if (kt > 0) dostores(kt - 1);

        if (kt + 1 < NTILES) stage(kt + 1, cur ^ 1);

        // ---- S = Q @ K^T : wave's 16 q-rows x 64 keys ----
        const char* kb = smem + KOFF + cur * 8192;
        f32x4 acc[4];
        #pragma unroll
        for (int n = 0; n < 4; ++n) acc[n] = (f32x4){0.f, 0.f, 0.f, 0.f};
        #pragma unroll
        for (int ks = 0; ks < 2; ++ks)
            #pragma unroll
            for (int nk = 0; nk < 4; ++nk) {
                unsigned row = nk * 16 + l15;
                s16x8 bk = *(const s16x8*)(kb + row * 128 +
                            ((ks * 64 + l4 * 16) ^ swzK(row)));
                acc[nk] = __builtin_amdgcn_mfma_f32_16x16x32_bf16(
                              aq[ks], bk, acc[nk], 0, 0, 0);
            }

        // ---- S -> wave-private LDS (bf16); same-wave ordering, no barrier ----
        #pragma unroll
        for (int nk = 0; nk < 4; ++nk)
            #pragma unroll
            for (int i = 0; i < 4; ++i) {
                unsigned q = l4 * 4 + (unsigned)i;
                unsigned key = nk * 16 + l15;
                *(unsigned short*)(sbase + q * 128 + ((key * 2) ^ swzS(q))) =
                    f2bf(acc[nk][i]);
            }

        // ---- readback into regs (stored at top of next tile) ----
        #pragma unroll
        for (int h = 0; h < 4; ++h) {
            unsigned q  = (h & 1) * 8 + rr;
            unsigned k4 = (h >> 1) * 32 + cc * 4;
            pbuf[h] = *(const u32x2*)(sbase + q * 128 + ((k4 * 2) ^ swzS(q)));
        }

        // ---- O += S @ V ----
        const char* vb = smem + VOFF + cur * 8192;
        #pragma unroll
        for (int ks = 0; ks < 2; ++ks) {
            s16x8 sa = *(const s16x8*)(sbase + l15 * 128 +
                        ((ks * 64 + l4 * 16) ^ swzS(l15)));
            #pragma unroll
            for (int nd = 0; nd < 4; ++nd) {
                unsigned row = nd * 16 + l15;
                s16x8 vf = *(const s16x8*)(vb + row * 128 +
                            ((ks * 64 + l4 * 16) ^ swzV(row)));
                acc_o[nd] = __builtin_amdgcn_mfma_f32_16x16x32_bf16(
                                sa, vf, acc_o[nd], 0, 0, 0);
            }
        }

        __syncthreads();   // one barrier per tile (dbuf flip)
    }

    dostores(NTILES - 1);

    // ---- write O ----
    float* op = og + ((size_t)b * SQL + qbase + wid * 16 + l4 * 4) * DD + l15;
    #pragma unroll
    for (int nd = 0; nd < 4; ++nd)
        #pragma unroll
        for (int i = 0; i < 4; ++i)
            __builtin_nontemporal_store(acc_o[nd][i], op + (size_t)i * DD + nd * 16);
}

extern "C" void kernel_launch(void* const* d_in, const int* in_sizes, int n_in,
                              void* d_out, int out_size, void* d_ws, size_t ws_size,
                              hipStream_t stream) {
    const float* q = (const float*)d_in[0];
    const float* k = (const float*)d_in[1];
    const float* v = (const float*)d_in[2];
    float* outp  = (float*)d_out;                      // [32][2048][64]
    float* attnp = outp + (size_t)NB * SQL * DD;       // [32][2048][2048]
    sdpa_fused<<<dim3(NB * (SQL / QBLK)), dim3(512), 0, stream>>>(q, k, v, outp, attnp);
}